// Round 7
// baseline (502.365 us; speedup 1.0000x reference)
//
#include <hip/hip_runtime.h>

#define BATCH 65536

typedef float f32x4 __attribute__((ext_vector_type(4)));
typedef _Float16 f16x8 __attribute__((ext_vector_type(8)));
typedef _Float16 f16x4 __attribute__((ext_vector_type(4)));

__device__ __forceinline__ void async_ld16(const void* g, void* l) {
  __builtin_amdgcn_global_load_lds(
      (const __attribute__((address_space(1))) void*)g,
      (__attribute__((address_space(3))) void*)l, 16, 0, 0);
}

__device__ __forceinline__ float act_f(float x, float a0, float a1, float a2,
                                       float a3, float a4) {
  float ax = fabsf(x);
  float e = __builtin_amdgcn_exp2f(ax * -2.8853900817779268f);
  float th = (1.0f - e) * __builtin_amdgcn_rcpf(1.0f + e);
  th = copysignf(th, x);
  float arg = fmaf(a1, x, a2);
  float rev = arg * 0.15915494309189535f;
  rev -= floorf(rev);
  float s = __builtin_amdgcn_sinf(rev);
  return fmaf(a3, x, fmaf(a0 * th, s, a4));
}

// split + transpose weights: W[K][N] fp32 -> Wt_hi/lo[N][K] fp16
__global__ __launch_bounds__(256) void splitT_k(const float* __restrict__ W,
                                                _Float16* __restrict__ hi,
                                                _Float16* __restrict__ lo,
                                                int K, int N) {
  const int i = blockIdx.x * 256 + threadIdx.x;
  if (i >= K * N) return;
  const int k = i / N, n = i % N;
  const float w = W[i];
  const _Float16 h = (_Float16)w;
  hi[(size_t)n * K + k] = h;
  lo[(size_t)n * K + k] = (_Float16)(w - (float)h);
}

// pack bias + a^T into Pt[6][N]
__global__ __launch_bounds__(256) void prep_params(const float* __restrict__ b,
                                                   const float* __restrict__ a,
                                                   float* __restrict__ Pt,
                                                   int N) {
  const int c = blockIdx.x * 256 + threadIdx.x;
  if (c >= N) return;
  Pt[c] = b[c];
#pragma unroll
  for (int j = 0; j < 5; ++j) Pt[(1 + j) * N + c] = a[c * 5 + j];
}

// 3-product compensation, SWAPPED operands: first arg = weight frag (A-op),
// second = activation frag (B-op) -> D = C^T layout: lane holds
// row = m16 (fixed), cols = quad*4 + r (consecutive).
__device__ __forceinline__ f32x4 mfma3s(f16x8 wh, f16x8 wl, f16x8 xh,
                                        f16x8 xl, f32x4 c) {
  c = __builtin_amdgcn_mfma_f32_16x16x32_f16(wh, xh, c, 0, 0, 0);
  c = __builtin_amdgcn_mfma_f32_16x16x32_f16(wh, xl, c, 0, 0, 0);
  c = __builtin_amdgcn_mfma_f32_16x16x32_f16(wl, xh, c, 0, 0, 0);
  return c;
}

// C = act @ Wt planes. Block tile (2*MT*16) x (2*NT*16), BK=32, 4 waves 2x2.
// A: fp32 [M][K] (AF32, LDS-staged, split in-register) or fp16 hi/lo planes.
// B: Wt[N][K] fp16 hi/lo planes (L2-hot). LDS XOR-swizzled at 16B granularity
// (fp16 rows 64B: seg^=((row>>1)&3); fp32 rows 128B: seg^=(row&7)).
// Epilogue (C^T acc): bias+act from Pt[6][N], f16x4/f32x4 stores; FINAL adds
// fused row-softmax (requires full N in one block).
// Grid: x = M-strips (FASTEST — r2-proven A-locality), y = N-tiles.
template <int MT, int NT, bool AF32, bool FINAL, int NW>
__global__ __launch_bounds__(256, NW) void gemm_act(
    const float* __restrict__ Af, const _Float16* __restrict__ Ahi,
    const _Float16* __restrict__ Alo, const _Float16* __restrict__ Bhi,
    const _Float16* __restrict__ Blo, const float* __restrict__ Pt,
    _Float16* __restrict__ Chi, _Float16* __restrict__ Clo,
    float* __restrict__ Cout, int K, int N) {
  constexpr int MB_ = 2 * MT * 16;  // block rows
  constexpr int NB_ = 2 * NT * 16;  // block cols
  __shared__ __align__(16) _Float16 sA[MB_ * 64];
  __shared__ __align__(16) _Float16 sB[NB_ * 64];

  const int tid = threadIdx.x;
  const int wv = tid >> 6, lane = tid & 63;
  const int wm = wv >> 1, wn = wv & 1;
  const int m16 = lane & 15, quad = lane >> 4;
  const int row0 = blockIdx.x * MB_;  // x = M fastest
  const int col0 = blockIdx.y * NB_;
  // staging lane decomposition + swizzled global segment
  const int rl4 = lane >> 2, sg4 = (lane & 3) ^ ((rl4 >> 1) & 3);  // 64B rows
  const int rl8 = lane >> 3, sg8 = (lane & 7) ^ rl8;               // 128B rows
  const int fswz = (quad ^ ((m16 >> 1) & 3)) * 8;  // fp16 frag-read swizzle

  f32x4 acc[MT][NT];
  const f32x4 zero = {0.f, 0.f, 0.f, 0.f};
#pragma unroll
  for (int i = 0; i < MT; ++i)
#pragma unroll
    for (int j = 0; j < NT; ++j) acc[i][j] = zero;

  const int nk = K >> 5;
  for (int kt = 0; kt < nk; ++kt) {
    const int k0 = kt << 5;
    // ---- stage A ----
    if constexpr (AF32) {
      float* sAf = (float*)sA;
      constexpr int PW = (MB_ / 8) / 4;  // 8-row chunks per wave
#pragma unroll
      for (int t = 0; t < PW; ++t) {
        const int c = wv * PW + t;
        const size_t ga = (size_t)(row0 + c * 8 + rl8) * K + k0 + sg8 * 4;
        async_ld16(Af + ga, (void*)&sAf[c * 256]);
      }
    } else {
      constexpr int PW = (MB_ / 16) / 4;  // 16-row chunks per wave
#pragma unroll
      for (int t = 0; t < PW; ++t) {
        const int c = wv * PW + t;
        const size_t ga = (size_t)(row0 + c * 16 + rl4) * K + k0 + sg4 * 8;
        async_ld16(Ahi + ga, (void*)&sA[c * 512]);
        async_ld16(Alo + ga, (void*)&sA[MB_ * 32 + c * 512]);
      }
    }
    // ---- stage B ----
    {
      constexpr int PW = (NB_ / 16) / 4;
#pragma unroll
      for (int t = 0; t < PW; ++t) {
        const int c = wv * PW + t;
        const size_t gb = (size_t)(col0 + c * 16 + rl4) * K + k0 + sg4 * 8;
        async_ld16(Bhi + gb, (void*)&sB[c * 512]);
        async_ld16(Blo + gb, (void*)&sB[NB_ * 32 + c * 512]);
      }
    }
    __syncthreads();

    // ---- A fragments ----
    f16x8 ah[MT], al[MT];
#pragma unroll
    for (int tm = 0; tm < MT; ++tm) {
      const int arow = wm * MT * 16 + tm * 16 + m16;
      if constexpr (AF32) {
        const float* sAf = (const float*)sA + arow * 32;
        const int rc7 = m16 & 7;
        const f32x4 x0 = *(const f32x4*)(sAf + ((2 * quad) ^ rc7) * 4);
        const f32x4 x1 = *(const f32x4*)(sAf + ((2 * quad + 1) ^ rc7) * 4);
#pragma unroll
        for (int j = 0; j < 4; ++j) {
          const _Float16 h0 = (_Float16)x0[j];
          ah[tm][j] = h0;
          al[tm][j] = (_Float16)(x0[j] - (float)h0);
          const _Float16 h1 = (_Float16)x1[j];
          ah[tm][4 + j] = h1;
          al[tm][4 + j] = (_Float16)(x1[j] - (float)h1);
        }
      } else {
        const int idx = arow * 32 + fswz;
        ah[tm] = *(const f16x8*)&sA[idx];
        al[tm] = *(const f16x8*)&sA[MB_ * 32 + idx];
      }
    }
    // ---- B fragments + MFMA (weight frag first -> C^T acc) ----
#pragma unroll
    for (int tn = 0; tn < NT; ++tn) {
      const int bcol = wn * NT * 16 + tn * 16 + m16;
      const int idx = bcol * 32 + fswz;
      const f16x8 bh = *(const f16x8*)&sB[idx];
      const f16x8 bl = *(const f16x8*)&sB[NB_ * 32 + idx];
#pragma unroll
      for (int tm = 0; tm < MT; ++tm)
        acc[tm][tn] = mfma3s(bh, bl, ah[tm], al[tm], acc[tm][tn]);
    }
    __syncthreads();
  }

  // ---- epilogue. acc (C^T): value[r] = C[rowbase+m16][colbase+quad*4+r] ----
  if constexpr (!FINAL) {
#pragma unroll
    for (int tn = 0; tn < NT; ++tn) {
      const int colb = col0 + wn * NT * 16 + tn * 16 + quad * 4;
      f32x4 P[6];
#pragma unroll
      for (int j = 0; j < 6; ++j) P[j] = *(const f32x4*)&Pt[j * N + colb];
#pragma unroll
      for (int tm = 0; tm < MT; ++tm) {
        const int row = row0 + wm * MT * 16 + tm * 16 + m16;
        f16x4 h4, l4;
#pragma unroll
        for (int r = 0; r < 4; ++r) {
          const float y = act_f(acc[tm][tn][r] + P[0][r], P[1][r], P[2][r],
                                P[3][r], P[4][r], P[5][r]);
          const _Float16 h = (_Float16)y;
          h4[r] = h;
          l4[r] = (_Float16)(y - (float)h);
        }
        const size_t o = (size_t)row * N + colb;
        *(f16x4*)&Chi[o] = h4;
        *(f16x4*)&Clo[o] = l4;
      }
    }
  } else {
    // bias + act, then fused softmax over N (full width in this block)
    const float L2E = 1.4426950408889634f;
    float mx[MT], sm[MT];
#pragma unroll
    for (int tm = 0; tm < MT; ++tm) mx[tm] = -1e30f;
#pragma unroll
    for (int tn = 0; tn < NT; ++tn) {
      const int colb = wn * NT * 16 + tn * 16 + quad * 4;
      f32x4 P[6];
#pragma unroll
      for (int j = 0; j < 6; ++j) P[j] = *(const f32x4*)&Pt[j * N + colb];
#pragma unroll
      for (int tm = 0; tm < MT; ++tm)
#pragma unroll
        for (int r = 0; r < 4; ++r) {
          const float y = act_f(acc[tm][tn][r] + P[0][r], P[1][r], P[2][r],
                                P[3][r], P[4][r], P[5][r]);
          acc[tm][tn][r] = y;
          mx[tm] = fmaxf(mx[tm], y);
        }
    }
#pragma unroll
    for (int tm = 0; tm < MT; ++tm) {
      mx[tm] = fmaxf(mx[tm], __shfl_xor(mx[tm], 16));
      mx[tm] = fmaxf(mx[tm], __shfl_xor(mx[tm], 32));
    }
#pragma unroll
    for (int tm = 0; tm < MT; ++tm) sm[tm] = 0.f;
#pragma unroll
    for (int tn = 0; tn < NT; ++tn)
#pragma unroll
      for (int tm = 0; tm < MT; ++tm)
#pragma unroll
        for (int r = 0; r < 4; ++r) {
          const float e =
              __builtin_amdgcn_exp2f((acc[tm][tn][r] - mx[tm]) * L2E);
          acc[tm][tn][r] = e;
          sm[tm] += e;
        }
#pragma unroll
    for (int tm = 0; tm < MT; ++tm) {
      sm[tm] += __shfl_xor(sm[tm], 16);
      sm[tm] += __shfl_xor(sm[tm], 32);
    }
    // cross-wave (wn pair) combine via LDS
    float* part = (float*)sA;
    if (quad == 0) {
#pragma unroll
      for (int tm = 0; tm < MT; ++tm) {
        const int rl = wm * MT * 16 + tm * 16 + m16;
        part[(wn * MB_ + rl) * 2 + 0] = mx[tm];
        part[(wn * MB_ + rl) * 2 + 1] = sm[tm];
      }
    }
    __syncthreads();
    float sc[MT];
#pragma unroll
    for (int tm = 0; tm < MT; ++tm) {
      const int rl = wm * MT * 16 + tm * 16 + m16;
      const float mo = part[((1 - wn) * MB_ + rl) * 2 + 0];
      const float so = part[((1 - wn) * MB_ + rl) * 2 + 1];
      const float M = fmaxf(mx[tm], mo);
      const float a = __builtin_amdgcn_exp2f((mx[tm] - M) * L2E);
      const float b = __builtin_amdgcn_exp2f((mo - M) * L2E);
      sc[tm] = a * __builtin_amdgcn_rcpf(fmaf(sm[tm], a, so * b));
    }
#pragma unroll
    for (int tn = 0; tn < NT; ++tn) {
      const int colb = wn * NT * 16 + tn * 16 + quad * 4;
#pragma unroll
      for (int tm = 0; tm < MT; ++tm) {
        const int row = row0 + wm * MT * 16 + tm * 16 + m16;
        f32x4 v = acc[tm][tn];
#pragma unroll
        for (int r = 0; r < 4; ++r) v[r] *= sc[tm];
        *(f32x4*)&Cout[(size_t)row * 256 + colb] = v;
      }
    }
  }
}

extern "C" void kernel_launch(void* const* d_in, const int* in_sizes, int n_in,
                              void* d_out, int out_size, void* d_ws,
                              size_t ws_size, hipStream_t stream) {
  const float* data = (const float*)d_in[0];
  const float* W1 = (const float*)d_in[1];
  const float* b1 = (const float*)d_in[2];
  const float* a1 = (const float*)d_in[3];
  const float* W2 = (const float*)d_in[4];
  const float* b2 = (const float*)d_in[5];
  const float* a2 = (const float*)d_in[6];
  const float* W3 = (const float*)d_in[7];
  const float* b3 = (const float*)d_in[8];
  const float* a3 = (const float*)d_in[9];
  float* out = (float*)d_out;

  char* ws = (char*)d_ws;
  const size_t KB = 1024;
  _Float16* w1hi = (_Float16*)(ws + 0 * KB);     // Wt1[512][256]
  _Float16* w1lo = (_Float16*)(ws + 256 * KB);
  _Float16* w2hi = (_Float16*)(ws + 512 * KB);   // Wt2[512][512]
  _Float16* w2lo = (_Float16*)(ws + 1024 * KB);
  _Float16* w3hi = (_Float16*)(ws + 1536 * KB);  // Wt3[256][512]
  _Float16* w3lo = (_Float16*)(ws + 1792 * KB);
  float* Pt1 = (float*)(ws + 2048 * KB);         // [6][512]
  float* Pt2 = (float*)(ws + 2064 * KB);         // [6][512]
  float* Pt3 = (float*)(ws + 2080 * KB);         // [6][256]
  // h1 hi/lo 64 MB each; h2lo 64 MB; h2hi aliases d_out (GEMM3 blocks are
  // full-N and row-disjoint; all A reads complete before epilogue writes)
  _Float16* h1hi = (_Float16*)(ws + 2112 * KB);
  _Float16* h1lo = (_Float16*)(ws + 2112 * KB + (size_t)BATCH * 512 * 2);
  _Float16* h2lo = (_Float16*)(ws + 2112 * KB + (size_t)BATCH * 512 * 4);
  _Float16* h2hi = (_Float16*)d_out;

  splitT_k<<<(256 * 512 + 255) / 256, 256, 0, stream>>>(W1, w1hi, w1lo, 256, 512);
  splitT_k<<<(512 * 512 + 255) / 256, 256, 0, stream>>>(W2, w2hi, w2lo, 512, 512);
  splitT_k<<<(512 * 256 + 255) / 256, 256, 0, stream>>>(W3, w3hi, w3lo, 512, 256);
  prep_params<<<2, 256, 0, stream>>>(b1, a1, Pt1, 512);
  prep_params<<<2, 256, 0, stream>>>(b2, a2, Pt2, 512);
  prep_params<<<1, 256, 0, stream>>>(b3, a3, Pt3, 256);

  // 128x128 tiles, grid x = M-strips FASTEST (r2-proven), y = N-tiles
  gemm_act<4, 4, true, false, 4><<<dim3(BATCH / 128, 4), 256, 0, stream>>>(
      data, nullptr, nullptr, w1hi, w1lo, Pt1, h1hi, h1lo, nullptr, 256, 512);
  gemm_act<4, 4, false, false, 4><<<dim3(BATCH / 128, 4), 256, 0, stream>>>(
      nullptr, h1hi, h1lo, w2hi, w2lo, Pt2, h2hi, h2lo, nullptr, 512, 512);
  // GEMM3: 128x256 full-N block with fused softmax
  gemm_act<4, 8, false, true, 2><<<dim3(BATCH / 128, 1), 256, 0, stream>>>(
      nullptr, h2hi, h2lo, w3hi, w3lo, Pt3, nullptr, nullptr, out, 512, 256);
}

// Round 8
// 472.584 us; speedup vs baseline: 1.0630x; 1.0630x over previous
//
#include <hip/hip_runtime.h>

#define BATCH 65536

typedef float f32x4 __attribute__((ext_vector_type(4)));
typedef _Float16 f16x8 __attribute__((ext_vector_type(8)));

__device__ __forceinline__ void async_ld16(const void* g, void* l) {
  __builtin_amdgcn_global_load_lds(
      (const __attribute__((address_space(1))) void*)g,
      (__attribute__((address_space(3))) void*)l, 16, 0, 0);
}

__device__ __forceinline__ float act_f(float x, float a0, float a1, float a2,
                                       float a3, float a4) {
  float ax = fabsf(x);
  float e = __builtin_amdgcn_exp2f(ax * -2.8853900817779268f);
  float th = (1.0f - e) * __builtin_amdgcn_rcpf(1.0f + e);
  th = copysignf(th, x);
  float arg = fmaf(a1, x, a2);
  float rev = arg * 0.15915494309189535f;
  rev -= floorf(rev);
  float s = __builtin_amdgcn_sinf(rev);
  return fmaf(a3, x, fmaf(a0 * th, s, a4));
}

// split + transpose weights: W[K][N] fp32 -> Wt_hi/lo[N][K] fp16
__global__ __launch_bounds__(256) void splitT_k(const float* __restrict__ W,
                                                _Float16* __restrict__ hi,
                                                _Float16* __restrict__ lo,
                                                int K, int N) {
  const int i = blockIdx.x * 256 + threadIdx.x;
  if (i >= K * N) return;
  const int k = i / N, n = i % N;
  const float w = W[i];
  const _Float16 h = (_Float16)w;
  hi[(size_t)n * K + k] = h;
  lo[(size_t)n * K + k] = (_Float16)(w - (float)h);
}

// pack bias + a^T into Pt[6][N]
__global__ __launch_bounds__(256) void prep_params(const float* __restrict__ b,
                                                   const float* __restrict__ a,
                                                   float* __restrict__ Pt,
                                                   int N) {
  const int c = blockIdx.x * 256 + threadIdx.x;
  if (c >= N) return;
  Pt[c] = b[c];
#pragma unroll
  for (int j = 0; j < 5; ++j) Pt[(1 + j) * N + c] = a[c * 5 + j];
}

// 3-product compensation, SWAPPED operands: first = weight frag (A-op),
// second = activation frag (B-op) -> D = C^T layout: lane holds
// row = m16, cols = quad*4 + r (consecutive).
__device__ __forceinline__ f32x4 mfma3s(f16x8 wh, f16x8 wl, f16x8 xh,
                                        f16x8 xl, f32x4 c) {
  c = __builtin_amdgcn_mfma_f32_16x16x32_f16(wh, xh, c, 0, 0, 0);
  c = __builtin_amdgcn_mfma_f32_16x16x32_f16(wh, xl, c, 0, 0, 0);
  c = __builtin_amdgcn_mfma_f32_16x16x32_f16(wl, xh, c, 0, 0, 0);
  return c;
}

// C = act @ Wt. Block 64 rows x 256 cols, BK=32, 4 waves side-by-side
// (wave = 64x64, MT=4 x NT=4; A-fragments shared by all waves -> broadcast).
// A: fp32 [M][K] (AF32) or fp16 hi/lo planes. B: Wt[N][K] hi/lo planes.
// LDS 16B-XOR swizzled (conflict-free, r5-proven).
// Epilogue !FINAL: act -> LDS fp32 (granule-XOR) -> readback 8-col units ->
// f16x8 hi + f16x8 lo 16B stores (full-line, no RMW).
// Epilogue FINAL: act + 4-wave fused softmax over N=256, f32x4 stores.
template <bool AF32, bool FINAL, int NW>
__global__ __launch_bounds__(256, NW) void gemm_act(
    const float* __restrict__ Af, const _Float16* __restrict__ Ahi,
    const _Float16* __restrict__ Alo, const _Float16* __restrict__ Bhi,
    const _Float16* __restrict__ Blo, const float* __restrict__ Pt,
    _Float16* __restrict__ Chi, _Float16* __restrict__ Clo,
    float* __restrict__ Cout, int K, int N) {
  __shared__ __align__(16) _Float16 smem[20480];  // 40 KB
  _Float16* sA = smem;                            // 8 KB
  _Float16* sB = smem + 4096;                     // 32 KB

  const int tid = threadIdx.x;
  const int wv = tid >> 6, lane = tid & 63;
  const int m16 = lane & 15, quad = lane >> 4;
  const int col0 = blockIdx.x * 256;  // x = N-tiles (<=2, r4-proven locality)
  const int row0 = blockIdx.y * 64;
  const int rl4 = lane >> 2, sg4 = (lane & 3) ^ ((rl4 >> 1) & 3);  // 64B rows
  const int rl8 = lane >> 3, sg8 = (lane & 7) ^ rl8;               // 128B rows
  const int fswz = (quad ^ ((m16 >> 1) & 3)) * 8;
  const int rc7 = m16 & 7;

  f32x4 acc[4][4];
  const f32x4 zero = {0.f, 0.f, 0.f, 0.f};
#pragma unroll
  for (int i = 0; i < 4; ++i)
#pragma unroll
    for (int j = 0; j < 4; ++j) acc[i][j] = zero;

  const int nk = K >> 5;
  for (int kt = 0; kt < nk; ++kt) {
    const int k0 = kt << 5;
    // ---- stage A (64 rows x 32 k) ----
    if constexpr (AF32) {
      float* sAf = (float*)sA;
#pragma unroll
      for (int t = 0; t < 2; ++t) {
        const int c = wv * 2 + t;  // 8 chunks of 8 rows
        const size_t ga = (size_t)(row0 + c * 8 + rl8) * K + k0 + sg8 * 4;
        async_ld16(Af + ga, (void*)&sAf[c * 256]);
      }
    } else {
      const int c = wv;  // 4 chunks of 16 rows per plane
      const size_t ga = (size_t)(row0 + c * 16 + rl4) * K + k0 + sg4 * 8;
      async_ld16(Ahi + ga, (void*)&sA[c * 512]);
      async_ld16(Alo + ga, (void*)&sA[2048 + c * 512]);
    }
    // ---- stage B (256 cols x 32 k, 2 planes) ----
#pragma unroll
    for (int t = 0; t < 4; ++t) {
      const int c = wv * 4 + t;
      const size_t gb = (size_t)(col0 + c * 16 + rl4) * K + k0 + sg4 * 8;
      async_ld16(Bhi + gb, (void*)&sB[c * 512]);
      async_ld16(Blo + gb, (void*)&sB[8192 + c * 512]);
    }
    __syncthreads();

    // ---- A fragments (same addresses in all waves -> broadcast) ----
    f16x8 ah[4], al[4];
#pragma unroll
    for (int tm = 0; tm < 4; ++tm) {
      const int arow = tm * 16 + m16;
      if constexpr (AF32) {
        const float* sAf = (const float*)sA + arow * 32;
        const f32x4 x0 = *(const f32x4*)(sAf + ((2 * quad) ^ rc7) * 4);
        const f32x4 x1 = *(const f32x4*)(sAf + ((2 * quad + 1) ^ rc7) * 4);
#pragma unroll
        for (int j = 0; j < 4; ++j) {
          const _Float16 h0 = (_Float16)x0[j];
          ah[tm][j] = h0;
          al[tm][j] = (_Float16)(x0[j] - (float)h0);
          const _Float16 h1 = (_Float16)x1[j];
          ah[tm][4 + j] = h1;
          al[tm][4 + j] = (_Float16)(x1[j] - (float)h1);
        }
      } else {
        const int idx = arow * 32 + fswz;
        ah[tm] = *(const f16x8*)&sA[idx];
        al[tm] = *(const f16x8*)&sA[2048 + idx];
      }
    }
    // ---- B fragments + MFMA ----
#pragma unroll
    for (int tn = 0; tn < 4; ++tn) {
      const int bcol = wv * 64 + tn * 16 + m16;
      const int idx = bcol * 32 + fswz;
      const f16x8 bh = *(const f16x8*)&sB[idx];
      const f16x8 bl = *(const f16x8*)&sB[8192 + idx];
#pragma unroll
      for (int tm = 0; tm < 4; ++tm)
        acc[tm][tn] = mfma3s(bh, bl, ah[tm], al[tm], acc[tm][tn]);
    }
    __syncthreads();
  }

  if constexpr (!FINAL) {
    // ---- epilogue: act -> LDS fp32 [64][128] (granule-XOR) -> full-line
    //      f16x8 hi/lo stores. Two passes over col-halves. ----
    float* ly = (float*)smem;
#pragma unroll
    for (int p = 0; p < 2; ++p) {
#pragma unroll
      for (int j = 0; j < 2; ++j) {
        const int tn = 2 * p + j;
        const int colb = col0 + wv * 64 + tn * 16 + quad * 4;
        f32x4 P[6];
#pragma unroll
        for (int q = 0; q < 6; ++q) P[q] = *(const f32x4*)&Pt[q * N + colb];
#pragma unroll
        for (int tm = 0; tm < 4; ++tm) {
          const int row = tm * 16 + m16;
          f32x4 y;
#pragma unroll
          for (int r = 0; r < 4; ++r)
            y[r] = act_f(acc[tm][tn][r] + P[0][r], P[1][r], P[2][r], P[3][r],
                         P[4][r], P[5][r]);
          const int g = (wv * 8 + j * 4 + quad) ^ (row & 7);
          *(f32x4*)&ly[row * 128 + g * 4] = y;
        }
      }
      __syncthreads();
#pragma unroll
      for (int i = 0; i < 4; ++i) {
        const int u = tid + 256 * i;
        const int row = u >> 4, oct = u & 15;
        const int g0 = (2 * oct) ^ (row & 7), g1 = (2 * oct + 1) ^ (row & 7);
        const f32x4 a = *(const f32x4*)&ly[row * 128 + g0 * 4];
        const f32x4 b = *(const f32x4*)&ly[row * 128 + g1 * 4];
        f16x8 h8, l8;
#pragma unroll
        for (int r = 0; r < 4; ++r) {
          const _Float16 ha = (_Float16)a[r];
          h8[r] = ha;
          l8[r] = (_Float16)(a[r] - (float)ha);
          const _Float16 hb = (_Float16)b[r];
          h8[4 + r] = hb;
          l8[4 + r] = (_Float16)(b[r] - (float)hb);
        }
        const int gcol = (oct >> 2) * 64 + p * 32 + (oct & 3) * 8;
        const size_t o = (size_t)(row0 + row) * N + col0 + gcol;
        *(f16x8*)&Chi[o] = h8;
        *(f16x8*)&Clo[o] = l8;
      }
      __syncthreads();
    }
  } else {
    // ---- epilogue: act + fused softmax over N=256 (4 waves x 64 cols) ----
    const float L2E = 1.4426950408889634f;
    float mx[4], sm[4];
#pragma unroll
    for (int tm = 0; tm < 4; ++tm) mx[tm] = -1e30f;
#pragma unroll
    for (int tn = 0; tn < 4; ++tn) {
      const int colb = wv * 64 + tn * 16 + quad * 4;
      f32x4 P[6];
#pragma unroll
      for (int q = 0; q < 6; ++q) P[q] = *(const f32x4*)&Pt[q * 256 + colb];
#pragma unroll
      for (int tm = 0; tm < 4; ++tm)
#pragma unroll
        for (int r = 0; r < 4; ++r) {
          const float y = act_f(acc[tm][tn][r] + P[0][r], P[1][r], P[2][r],
                                P[3][r], P[4][r], P[5][r]);
          acc[tm][tn][r] = y;
          mx[tm] = fmaxf(mx[tm], y);
        }
    }
#pragma unroll
    for (int tm = 0; tm < 4; ++tm) {
      mx[tm] = fmaxf(mx[tm], __shfl_xor(mx[tm], 16));
      mx[tm] = fmaxf(mx[tm], __shfl_xor(mx[tm], 32));
    }
    // cross-wave max via LDS part[wv][64]
    float* part = (float*)smem;
    if (quad == 0) {
#pragma unroll
      for (int tm = 0; tm < 4; ++tm) part[wv * 64 + tm * 16 + m16] = mx[tm];
    }
    __syncthreads();
#pragma unroll
    for (int tm = 0; tm < 4; ++tm) {
      const int rl = tm * 16 + m16;
      float M = part[rl];
#pragma unroll
      for (int w = 1; w < 4; ++w) M = fmaxf(M, part[w * 64 + rl]);
      mx[tm] = M;
      sm[tm] = 0.f;
    }
#pragma unroll
    for (int tn = 0; tn < 4; ++tn)
#pragma unroll
      for (int tm = 0; tm < 4; ++tm)
#pragma unroll
        for (int r = 0; r < 4; ++r) {
          const float e =
              __builtin_amdgcn_exp2f((acc[tm][tn][r] - mx[tm]) * L2E);
          acc[tm][tn][r] = e;
          sm[tm] += e;
        }
#pragma unroll
    for (int tm = 0; tm < 4; ++tm) {
      sm[tm] += __shfl_xor(sm[tm], 16);
      sm[tm] += __shfl_xor(sm[tm], 32);
    }
    __syncthreads();
    if (quad == 0) {
#pragma unroll
      for (int tm = 0; tm < 4; ++tm)
        part[256 + wv * 64 + tm * 16 + m16] = sm[tm];
    }
    __syncthreads();
    float sc[4];
#pragma unroll
    for (int tm = 0; tm < 4; ++tm) {
      const int rl = tm * 16 + m16;
      float S = part[256 + rl];
#pragma unroll
      for (int w = 1; w < 4; ++w) S += part[256 + w * 64 + rl];
      sc[tm] = __builtin_amdgcn_rcpf(S);
    }
#pragma unroll
    for (int tn = 0; tn < 4; ++tn) {
      const int colb = wv * 64 + tn * 16 + quad * 4;
#pragma unroll
      for (int tm = 0; tm < 4; ++tm) {
        const int row = row0 + tm * 16 + m16;
        f32x4 v = acc[tm][tn];
#pragma unroll
        for (int r = 0; r < 4; ++r) v[r] *= sc[tm];
        *(f32x4*)&Cout[(size_t)row * 256 + colb] = v;
      }
    }
  }
}

extern "C" void kernel_launch(void* const* d_in, const int* in_sizes, int n_in,
                              void* d_out, int out_size, void* d_ws,
                              size_t ws_size, hipStream_t stream) {
  const float* data = (const float*)d_in[0];
  const float* W1 = (const float*)d_in[1];
  const float* b1 = (const float*)d_in[2];
  const float* a1 = (const float*)d_in[3];
  const float* W2 = (const float*)d_in[4];
  const float* b2 = (const float*)d_in[5];
  const float* a2 = (const float*)d_in[6];
  const float* W3 = (const float*)d_in[7];
  const float* b3 = (const float*)d_in[8];
  const float* a3 = (const float*)d_in[9];
  float* out = (float*)d_out;

  char* ws = (char*)d_ws;
  const size_t KB = 1024;
  _Float16* w1hi = (_Float16*)(ws + 0 * KB);     // Wt1[512][256]
  _Float16* w1lo = (_Float16*)(ws + 256 * KB);
  _Float16* w2hi = (_Float16*)(ws + 512 * KB);   // Wt2[512][512]
  _Float16* w2lo = (_Float16*)(ws + 1024 * KB);
  _Float16* w3hi = (_Float16*)(ws + 1536 * KB);  // Wt3[256][512]
  _Float16* w3lo = (_Float16*)(ws + 1792 * KB);
  float* Pt1 = (float*)(ws + 2048 * KB);         // [6][512]
  float* Pt2 = (float*)(ws + 2064 * KB);         // [6][512]
  float* Pt3 = (float*)(ws + 2080 * KB);         // [6][256]
  // h1 hi/lo 64 MB each; h2lo 64 MB; h2hi aliases d_out (GEMM3 is full-N,
  // row-disjoint; A reads complete before its epilogue writes)
  _Float16* h1hi = (_Float16*)(ws + 2112 * KB);
  _Float16* h1lo = (_Float16*)(ws + 2112 * KB + (size_t)BATCH * 512 * 2);
  _Float16* h2lo = (_Float16*)(ws + 2112 * KB + (size_t)BATCH * 512 * 4);
  _Float16* h2hi = (_Float16*)d_out;

  splitT_k<<<(256 * 512 + 255) / 256, 256, 0, stream>>>(W1, w1hi, w1lo, 256, 512);
  splitT_k<<<(512 * 512 + 255) / 256, 256, 0, stream>>>(W2, w2hi, w2lo, 512, 512);
  splitT_k<<<(512 * 256 + 255) / 256, 256, 0, stream>>>(W3, w3hi, w3lo, 512, 256);
  prep_params<<<2, 256, 0, stream>>>(b1, a1, Pt1, 512);
  prep_params<<<2, 256, 0, stream>>>(b2, a2, Pt2, 512);
  prep_params<<<1, 256, 0, stream>>>(b3, a3, Pt3, 256);

  // 64x256 blocks; grid x = N-tiles (2 strip-mates, r4-proven A-locality)
  gemm_act<true, false, 4><<<dim3(2, BATCH / 64), 256, 0, stream>>>(
      data, nullptr, nullptr, w1hi, w1lo, Pt1, h1hi, h1lo, nullptr, 256, 512);
  gemm_act<false, false, 4><<<dim3(2, BATCH / 64), 256, 0, stream>>>(
      nullptr, h1hi, h1lo, w2hi, w2lo, Pt2, h2hi, h2lo, nullptr, 512, 512);
  gemm_act<false, true, 3><<<dim3(1, BATCH / 64), 256, 0, stream>>>(
      nullptr, h2hi, h2lo, w3hi, w3lo, Pt3, nullptr, nullptr, out, 512, 256);
}